// Round 2
// baseline (2439.330 us; speedup 1.0000x reference)
//
#include <hip/hip_runtime.h>
#include <math.h>

// Problem constants
#define BB   4
#define SS   1024
#define BSR  4096          // B*S rows
#define VV   256
#define KDIM 64
#define HH   8
#define TT   4
#define EPSV 1e-3f
#define SCL  0.125f        // KD^-0.5

typedef float f4 __attribute__((ext_vector_type(4)));

#define LDP 68             // padded LDS stride (68*4B = 272B, 16B-aligned rows)

// ---------------------------------------------------------------------------
// 64x64 fp32 GEMM core, K=256, lda fixed 256. Block = 256 threads (16x16),
// each thread owns a 4x4 microtile. acc[i][j]: row ty*4+i, col tx*4+j.
// ---------------------------------------------------------------------------
__device__ __forceinline__ void gemm_core(
    const float* __restrict__ A,   // pre-offset to tile row 0, lda=256
    const float* __restrict__ Bm,  // pre-offset to tile col 0, ldb param
    int ldb,
    float acc[4][4],
    float (*As)[LDP], float (*Bs)[LDP])
{
  const int tid = threadIdx.x;
  const int tx = tid & 15, ty = tid >> 4;
#pragma unroll
  for (int i = 0; i < 4; i++)
#pragma unroll
    for (int j = 0; j < 4; j++) acc[i][j] = 0.f;

  for (int k0 = 0; k0 < 256; k0 += 16) {
#pragma unroll
    for (int l = 0; l < 4; l++) {
      int e = tid + l * 256;
      int r = e >> 4, kk = e & 15;          // A tile: 64 rows x 16 k
      As[kk][r] = A[r * 256 + k0 + kk];
      int rb = e >> 6, nn = e & 63;         // B tile: 16 k x 64 n
      Bs[rb][nn] = Bm[(k0 + rb) * ldb + nn];
    }
    __syncthreads();
#pragma unroll
    for (int kk = 0; kk < 16; kk++) {
      f4 av = *(const f4*)&As[kk][ty * 4];
      f4 bv = *(const f4*)&Bs[kk][tx * 4];
#pragma unroll
      for (int i = 0; i < 4; i++)
#pragma unroll
        for (int j = 0; j < 4; j++)
          acc[i][j] += av[i] * bv[j];
    }
    __syncthreads();
  }
}

// ---------------------------------------------------------------------------
// net0 = x @ W_in, broadcast into all H head slots of `net`
// grid: (64 m-tiles, 4 n-tiles)
// ---------------------------------------------------------------------------
__global__ __launch_bounds__(256) void k_in_dense(
    const float* __restrict__ x, const float* __restrict__ Win,
    float* __restrict__ net)
{
  __shared__ __align__(16) float As[16][LDP];
  __shared__ __align__(16) float Bs[16][LDP];
  const int mt = blockIdx.x, nt = blockIdx.y;
  float acc[4][4];
  gemm_core(x + mt * 64 * 256, Win + nt * 64, 256, acc, As, Bs);
  const int tx = threadIdx.x & 15, ty = threadIdx.x >> 4;
#pragma unroll
  for (int i = 0; i < 4; i++) {
    f4 v;
#pragma unroll
    for (int j = 0; j < 4; j++) v[j] = acc[i][j];
    int row = mt * 64 + ty * 4 + i;
    int col = nt * 64 + tx * 4;
    for (int h = 0; h < HH; h++)
      *(f4*)&net[(size_t)h * 1048576 + row * 256 + col] = v;
  }
}

// ---------------------------------------------------------------------------
// Fused QKV: q = net@Wq[h][t], k = net@Wk[h][t], v = net@Wv[h][t]
// grid: (64 m-tiles, 6 n-tiles [0:q 1:k 2..5:v], 8 heads)
// ---------------------------------------------------------------------------
__global__ __launch_bounds__(256) void k_qkv(
    const float* __restrict__ net,
    const float* __restrict__ Wq, const float* __restrict__ Wk,
    const float* __restrict__ Wv,
    float* __restrict__ qb, float* __restrict__ kb, float* __restrict__ vb,
    int t)
{
  __shared__ __align__(16) float As[16][LDP];
  __shared__ __align__(16) float Bs[16][LDP];
  const int mt = blockIdx.x, nt = blockIdx.y, h = blockIdx.z;
  const float* A = net + (size_t)h * 1048576 + mt * 64 * 256;
  const float* Bm; int ldb; float* Cp; int ldc;
  if (nt == 0)      { Bm = Wq + (size_t)(h * TT + t) * VV * KDIM; ldb = KDIM;
                      Cp = qb + (size_t)h * 262144 + mt * 64 * KDIM; ldc = KDIM; }
  else if (nt == 1) { Bm = Wk + (size_t)(h * TT + t) * VV * KDIM; ldb = KDIM;
                      Cp = kb + (size_t)h * 262144 + mt * 64 * KDIM; ldc = KDIM; }
  else              { int c0 = (nt - 2) * 64;
                      Bm = Wv + (size_t)(h * TT + t) * VV * VV + c0; ldb = VV;
                      Cp = vb + (size_t)h * 1048576 + mt * 64 * VV + c0; ldc = VV; }
  float acc[4][4];
  gemm_core(A, Bm, ldb, acc, As, Bs);
  const int tx = threadIdx.x & 15, ty = threadIdx.x >> 4;
#pragma unroll
  for (int i = 0; i < 4; i++) {
    f4 v;
#pragma unroll
    for (int j = 0; j < 4; j++) v[j] = acc[i][j];
    *(f4*)&Cp[(ty * 4 + i) * ldc + tx * 4] = v;
  }
}

// ---------------------------------------------------------------------------
// tmp = net + relu(net @ Wd[h][t])
// grid: (64, 4, 8)
// ---------------------------------------------------------------------------
__global__ __launch_bounds__(256) void k_dense(
    const float* __restrict__ net, const float* __restrict__ Wd,
    float* __restrict__ tmp, int t)
{
  __shared__ __align__(16) float As[16][LDP];
  __shared__ __align__(16) float Bs[16][LDP];
  const int mt = blockIdx.x, nt = blockIdx.y, h = blockIdx.z;
  const float* A = net + (size_t)h * 1048576 + mt * 64 * 256;
  const float* Bm = Wd + (size_t)(h * TT + t) * VV * VV + nt * 64;
  float acc[4][4];
  gemm_core(A, Bm, 256, acc, As, Bs);
  const int tx = threadIdx.x & 15, ty = threadIdx.x >> 4;
#pragma unroll
  for (int i = 0; i < 4; i++) {
    int row = mt * 64 + ty * 4 + i;
    int col = nt * 64 + tx * 4;
    f4 nv = *(const f4*)&net[(size_t)h * 1048576 + row * 256 + col];
    f4 ov;
#pragma unroll
    for (int j = 0; j < 4; j++) ov[j] = nv[j] + fmaxf(acc[i][j], 0.f);
    *(f4*)&tmp[(size_t)h * 1048576 + row * 256 + col] = ov;
  }
}

// ---------------------------------------------------------------------------
// Flash attention (full, no mask): per (h, b, 64-row q tile), online softmax.
// tmp[h][b*S+row][c] = softmax(Q K^T * scale) @ V
// grid: (16 itiles, 4 batch, 8 heads), 256 threads (16x16).
// Thread (tx,ty): q-rows ty*4+i; O cols (cc*64 + tx*4 + m).
// ---------------------------------------------------------------------------
__global__ __launch_bounds__(256) void k_attn(
    const float* __restrict__ qb, const float* __restrict__ kb,
    const float* __restrict__ vb, float* __restrict__ ob)
{
  __shared__ __align__(16) float Qts[KDIM][LDP];   // Q transposed: [kd][row]
  __shared__ __align__(16) float KVs[64][LDP];     // K transposed [kd][j] / V chunk [j][c]
  __shared__ __align__(16) float Pts[64][LDP];     // P transposed: [j][row]
  const int it = blockIdx.x, b = blockIdx.y, h = blockIdx.z;
  const int tid = threadIdx.x, tx = tid & 15, ty = tid >> 4;
  const float* Q  = qb + (size_t)h * 262144 + b * 65536 + it * 64 * KDIM;
  const float* K  = kb + (size_t)h * 262144 + b * 65536;
  const float* Vp = vb + (size_t)h * 1048576 + b * 262144;

  float O[4][16];
#pragma unroll
  for (int i = 0; i < 4; i++)
#pragma unroll
    for (int o = 0; o < 16; o++) O[i][o] = 0.f;
  float m[4], l[4];
#pragma unroll
  for (int i = 0; i < 4; i++) { m[i] = -1e30f; l[i] = 0.f; }

  // load Q tile transposed (once)
#pragma unroll
  for (int ldx = 0; ldx < 16; ldx++) {
    int e = tid + ldx * 256;
    int r = e >> 6, kd = e & 63;
    Qts[kd][r] = Q[r * KDIM + kd];
  }

  for (int jt = 0; jt < 16; jt++) {
    __syncthreads();  // prev PV reads done; Q visible on first iter
    // load K tile transposed
#pragma unroll
    for (int ldx = 0; ldx < 16; ldx++) {
      int e = tid + ldx * 256;
      int j = e >> 6, kd = e & 63;
      KVs[kd][j] = K[(jt * 64 + j) * KDIM + kd];
    }
    __syncthreads();

    // S = Q K^T for 4x4 microtile
    float s[4][4];
#pragma unroll
    for (int i = 0; i < 4; i++)
#pragma unroll
      for (int j = 0; j < 4; j++) s[i][j] = 0.f;
#pragma unroll 16
    for (int kd = 0; kd < 64; kd++) {
      f4 aq = *(const f4*)&Qts[kd][ty * 4];
      f4 ak = *(const f4*)&KVs[kd][tx * 4];
#pragma unroll
      for (int i = 0; i < 4; i++)
#pragma unroll
        for (int j = 0; j < 4; j++)
          s[i][j] += aq[i] * ak[j];
    }

    // online softmax (row state replicated across tx-group; shfl over 16 lanes)
#pragma unroll
    for (int i = 0; i < 4; i++) {
#pragma unroll
      for (int j = 0; j < 4; j++) s[i][j] *= SCL;
      float mloc = fmaxf(fmaxf(s[i][0], s[i][1]), fmaxf(s[i][2], s[i][3]));
      for (int d = 1; d < 16; d <<= 1)
        mloc = fmaxf(mloc, __shfl_xor(mloc, d, 64));
      float mnew = fmaxf(m[i], mloc);
      float alpha = __expf(m[i] - mnew);
      float ls = 0.f;
#pragma unroll
      for (int j = 0; j < 4; j++) { s[i][j] = __expf(s[i][j] - mnew); ls += s[i][j]; }
      for (int d = 1; d < 16; d <<= 1)
        ls += __shfl_xor(ls, d, 64);
      l[i] = l[i] * alpha + ls;
      m[i] = mnew;
#pragma unroll
      for (int o = 0; o < 16; o++) O[i][o] *= alpha;
#pragma unroll
      for (int j = 0; j < 4; j++) Pts[tx * 4 + j][ty * 4 + i] = s[i][j];
    }

    // PV: stream V in 64-col chunks through KVs
    for (int cc = 0; cc < 4; cc++) {
      __syncthreads();   // S-phase reads of KVs + prev chunk PV done; Pts visible
#pragma unroll
      for (int ldx = 0; ldx < 16; ldx++) {   // 64x64 chunk = 4096 elems = 16*256
        int e = tid + ldx * 256;
        int j = e >> 6, kloc = e & 63;
        KVs[j][kloc] = Vp[(jt * 64 + j) * VV + cc * 64 + kloc];
      }
      __syncthreads();
#pragma unroll 4
      for (int j = 0; j < 64; j++) {
        f4 pv = *(const f4*)&Pts[j][ty * 4];
        f4 vv = *(const f4*)&KVs[j][tx * 4];
#pragma unroll
        for (int i = 0; i < 4; i++)
#pragma unroll
          for (int mm = 0; mm < 4; mm++)
            O[i][cc * 4 + mm] += pv[i] * vv[mm];
      }
    }
  }

  // epilogue: normalize by l, store
#pragma unroll
  for (int i = 0; i < 4; i++) {
    float linv = 1.f / l[i];
    int row = it * 64 + ty * 4 + i;
    float* dst = ob + (size_t)h * 1048576 + b * 262144 + row * 256;
#pragma unroll
    for (int cc = 0; cc < 4; cc++) {
      f4 v;
#pragma unroll
      for (int mm = 0; mm < 4; mm++) v[mm] = O[i][cc * 4 + mm] * linv;
      *(f4*)&dst[cc * 64 + tx * 4] = v;
    }
  }
}

// ---------------------------------------------------------------------------
// BN stats: per (h, channel) sum and sumsq of y over 4096 rows,
// y = a (+ b if addB). grid: (64 row-blocks, 8 heads), 256 threads = channels.
// ---------------------------------------------------------------------------
__global__ __launch_bounds__(256) void k_bnstats(
    const float* __restrict__ a, const float* __restrict__ b,
    float* __restrict__ stats, int addB)
{
  const int h = blockIdx.y, r0 = blockIdx.x * 64, c = threadIdx.x;
  const float* pa = a + (size_t)h * 1048576 + r0 * 256 + c;
  float s = 0.f, s2 = 0.f;
  if (addB) {
    const float* pb = b + (size_t)h * 1048576 + r0 * 256 + c;
    for (int r = 0; r < 64; r++) {
      float y = pa[r * 256] + pb[r * 256];
      s += y; s2 += y * y;
    }
  } else {
    for (int r = 0; r < 64; r++) {
      float y = pa[r * 256];
      s += y; s2 += y * y;
    }
  }
  atomicAdd(&stats[(h * 256 + c) * 2], s);
  atomicAdd(&stats[(h * 256 + c) * 2 + 1], s2);
}

// ---------------------------------------------------------------------------
// BN apply: dst = (y - mean) * rsqrt(var+eps) * gamma + beta.
// transposed=1 writes d_out in [B,S,H,V] layout.
// grid: (64, 8), 256 threads.
// ---------------------------------------------------------------------------
__global__ __launch_bounds__(256) void k_bnapply(
    const float* __restrict__ a, const float* __restrict__ b,
    const float* __restrict__ stats,
    const float* __restrict__ gamma, const float* __restrict__ beta,
    float* __restrict__ dst, int t, int addB, int transposed)
{
  const int h = blockIdx.y, r0 = blockIdx.x * 64, c = threadIdx.x;
  float s  = stats[(h * 256 + c) * 2];
  float s2 = stats[(h * 256 + c) * 2 + 1];
  float mean = s * (1.f / 4096.f);
  float var  = s2 * (1.f / 4096.f) - mean * mean;
  float inv  = rsqrtf(var + EPSV);
  float g  = gamma[(h * TT + t) * 256 + c] * inv;
  float bt = beta[(h * TT + t) * 256 + c];
  const float* pa = a + (size_t)h * 1048576 + r0 * 256 + c;
  const float* pb = addB ? (b + (size_t)h * 1048576 + r0 * 256 + c) : nullptr;
  for (int r = 0; r < 64; r++) {
    float y = pa[r * 256];
    if (addB) y += pb[r * 256];
    float o = (y - mean) * g + bt;
    int rg = r0 + r;
    if (transposed) dst[((size_t)rg * HH + h) * 256 + c] = o;
    else            dst[(size_t)h * 1048576 + rg * 256 + c] = o;
  }
}

// ---------------------------------------------------------------------------
extern "C" void kernel_launch(void* const* d_in, const int* in_sizes, int n_in,
                              void* d_out, int out_size, void* d_ws, size_t ws_size,
                              hipStream_t stream)
{
  const float* x   = (const float*)d_in[0];
  const float* Win = (const float*)d_in[1];
  const float* Wq  = (const float*)d_in[2];
  const float* Wk  = (const float*)d_in[3];
  const float* Wv  = (const float*)d_in[4];
  const float* Wd  = (const float*)d_in[5];
  const float* g1  = (const float*)d_in[6];
  const float* b1  = (const float*)d_in[7];
  const float* g2  = (const float*)d_in[8];
  const float* b2  = (const float*)d_in[9];
  float* out = (float*)d_out;
  float* ws  = (float*)d_ws;

  float* net   = ws;                          // H*BS*V           =  8,388,608 f
  float* qb    = net + 8388608;               // H*BS*KD          =  2,097,152 f
  float* kb    = qb + 2097152;                // H*BS*KD          =  2,097,152 f
  float* vb    = kb + 2097152;                // H*BS*V           =  8,388,608 f
  float* tmp   = vb + 8388608;                // H*BS*V           =  8,388,608 f
  float* stats = tmp + 8388608;               // 8 phases * H*V*2 =     32,768 f

  // zero all BN-stats phase buffers (ws is poisoned 0xAA before every launch)
  hipMemsetAsync(stats, 0, 8 * HH * VV * 2 * sizeof(float), stream);

  k_in_dense<<<dim3(64, 4), 256, 0, stream>>>(x, Win, net);

  for (int t = 0; t < TT; t++) {
    k_qkv<<<dim3(64, 6, 8), 256, 0, stream>>>(net, Wq, Wk, Wv, qb, kb, vb, t);
    k_attn<<<dim3(16, 4, 8), 256, 0, stream>>>(qb, kb, vb, tmp);

    float* st1 = stats + (t * 2 + 0) * HH * VV * 2;
    k_bnstats<<<dim3(64, 8), 256, 0, stream>>>(net, tmp, st1, 1);
    k_bnapply<<<dim3(64, 8), 256, 0, stream>>>(net, tmp, st1, g1, b1, net, t, 1, 0);

    k_dense<<<dim3(64, 4, 8), 256, 0, stream>>>(net, Wd, tmp, t);

    float* st2 = stats + (t * 2 + 1) * HH * VV * 2;
    k_bnstats<<<dim3(64, 8), 256, 0, stream>>>(tmp, nullptr, st2, 0);
    if (t < TT - 1)
      k_bnapply<<<dim3(64, 8), 256, 0, stream>>>(tmp, nullptr, st2, g2, b2, net, t, 0, 0);
    else
      k_bnapply<<<dim3(64, 8), 256, 0, stream>>>(tmp, nullptr, st2, g2, b2, out, t, 0, 1);
  }
}

// Round 4
// 1637.761 us; speedup vs baseline: 1.4894x; 1.4894x over previous
//
#include <hip/hip_runtime.h>
#include <hip/hip_bf16.h>
#include <math.h>

// Problem constants
#define BB   4
#define SS   1024
#define BSR  4096          // B*S rows
#define VV   256
#define KDIM 64
#define HH   8
#define TT   4
#define EPSV 1e-3f
#define SCL  0.125f        // KD^-0.5

typedef float f4 __attribute__((ext_vector_type(4)));
typedef short bf8 __attribute__((ext_vector_type(8)));   // 8 bf16 = 4 VGPRs
typedef short s4v __attribute__((ext_vector_type(4)));

#define LDP 68             // fp32 GEMM LDS stride (floats)
#define LQP 68             // fp32 attention LDS stride (floats)
#define LKP 72             // bf16 attention LDS stride (shorts; 144B = 9*16B)

__device__ __forceinline__ short f2bf(float x) {
  __hip_bfloat16 h = __float2bfloat16(x);   // RNE
  return *reinterpret_cast<short*>(&h);
}
__device__ __forceinline__ float bf2f(short h) {
  union { unsigned u; float f; } cv;
  cv.u = ((unsigned)(unsigned short)h) << 16;
  return cv.f;
}

// ---------------------------------------------------------------------------
// 64x64 fp32 GEMM core, K=256, lda fixed 256. Block = 256 threads (16x16),
// each thread owns a 4x4 microtile. acc[i][j]: row ty*4+i, col tx*4+j.
// ---------------------------------------------------------------------------
__device__ __forceinline__ void gemm_core(
    const float* __restrict__ A,   // pre-offset to tile row 0, lda=256
    const float* __restrict__ Bm,  // pre-offset to tile col 0, ldb param
    int ldb,
    float acc[4][4],
    float (*As)[LDP], float (*Bs)[LDP])
{
  const int tid = threadIdx.x;
  const int tx = tid & 15, ty = tid >> 4;
#pragma unroll
  for (int i = 0; i < 4; i++)
#pragma unroll
    for (int j = 0; j < 4; j++) acc[i][j] = 0.f;

  for (int k0 = 0; k0 < 256; k0 += 16) {
#pragma unroll
    for (int l = 0; l < 4; l++) {
      int e = tid + l * 256;
      int r = e >> 4, kk = e & 15;          // A tile: 64 rows x 16 k
      As[kk][r] = A[r * 256 + k0 + kk];
      int rb = e >> 6, nn = e & 63;         // B tile: 16 k x 64 n
      Bs[rb][nn] = Bm[(k0 + rb) * ldb + nn];
    }
    __syncthreads();
#pragma unroll
    for (int kk = 0; kk < 16; kk++) {
      f4 av = *(const f4*)&As[kk][ty * 4];
      f4 bv = *(const f4*)&Bs[kk][tx * 4];
#pragma unroll
      for (int i = 0; i < 4; i++)
#pragma unroll
        for (int j = 0; j < 4; j++)
          acc[i][j] += av[i] * bv[j];
    }
    __syncthreads();
  }
}

// ---------------------------------------------------------------------------
// net0 = x @ W_in, broadcast into all H head slots of `net`
// ---------------------------------------------------------------------------
__global__ __launch_bounds__(256) void k_in_dense(
    const float* __restrict__ x, const float* __restrict__ Win,
    float* __restrict__ net)
{
  __shared__ __align__(16) float As[16][LDP];
  __shared__ __align__(16) float Bs[16][LDP];
  const int mt = blockIdx.x, nt = blockIdx.y;
  float acc[4][4];
  gemm_core(x + mt * 64 * 256, Win + nt * 64, 256, acc, As, Bs);
  const int tx = threadIdx.x & 15, ty = threadIdx.x >> 4;
#pragma unroll
  for (int i = 0; i < 4; i++) {
    f4 v;
#pragma unroll
    for (int j = 0; j < 4; j++) v[j] = acc[i][j];
    int row = mt * 64 + ty * 4 + i;
    int col = nt * 64 + tx * 4;
    for (int h = 0; h < HH; h++)
      *(f4*)&net[(size_t)h * 1048576 + row * 256 + col] = v;
  }
}

// ---------------------------------------------------------------------------
// Fused QKV. Epilogues for the attention consumer:
//   qtg, ktg: fp32 TRANSPOSED per (h,b): [h*4+b][feat(64)][s(1024)]
//   vth, vtl: bf16 hi/lo split of v, TRANSPOSED: [h*4+b][vcol(256)][s(1024)]
// grid: (64 m-tiles, 6 n-tiles [0:q 1:k 2..5:v], 8 heads)
// ---------------------------------------------------------------------------
__global__ __launch_bounds__(256) void k_qkv(
    const float* __restrict__ net,
    const float* __restrict__ Wq, const float* __restrict__ Wk,
    const float* __restrict__ Wv,
    float* __restrict__ qtg, float* __restrict__ ktg,
    short* __restrict__ vth, short* __restrict__ vtl,
    int t)
{
  __shared__ __align__(16) float As[16][LDP];
  __shared__ __align__(16) float Bs[16][LDP];
  const int mt = blockIdx.x, nt = blockIdx.y, h = blockIdx.z;
  const float* A = net + (size_t)h * 1048576 + mt * 64 * 256;
  const float* Bm; int ldb;
  if (nt == 0)      { Bm = Wq + (size_t)(h * TT + t) * VV * KDIM; ldb = KDIM; }
  else if (nt == 1) { Bm = Wk + (size_t)(h * TT + t) * VV * KDIM; ldb = KDIM; }
  else              { Bm = Wv + (size_t)(h * TT + t) * VV * VV + (nt - 2) * 64; ldb = VV; }
  float acc[4][4];
  gemm_core(A, Bm, ldb, acc, As, Bs);
  const int tx = threadIdx.x & 15, ty = threadIdx.x >> 4;

  if (nt == 0) {
#pragma unroll
    for (int i = 0; i < 4; i++) {
      int row = mt * 64 + ty * 4 + i;
      int b_ = row >> 10, sI = row & 1023;
#pragma unroll
      for (int j = 0; j < 4; j++)
        qtg[((size_t)(h * 4 + b_) * 64 + tx * 4 + j) * 1024 + sI] = acc[i][j];
    }
  } else if (nt == 1) {
#pragma unroll
    for (int i = 0; i < 4; i++) {
      int row = mt * 64 + ty * 4 + i;
      int b_ = row >> 10, sI = row & 1023;
#pragma unroll
      for (int j = 0; j < 4; j++)
        ktg[((size_t)(h * 4 + b_) * 64 + tx * 4 + j) * 1024 + sI] = acc[i][j];
    }
  } else {
    const int c0 = (nt - 2) * 64;
#pragma unroll
    for (int i = 0; i < 4; i++) {
      int row = mt * 64 + ty * 4 + i;
      int b_ = row >> 10, sI = row & 1023;
#pragma unroll
      for (int j = 0; j < 4; j++) {
        float v = acc[i][j];
        short hi = f2bf(v);
        short lo = f2bf(v - bf2f(hi));
        size_t idx = ((size_t)(h * 4 + b_) * 256 + c0 + tx * 4 + j) * 1024 + sI;
        vth[idx] = hi;
        vtl[idx] = lo;
      }
    }
  }
}

// ---------------------------------------------------------------------------
// tmp = net + relu(net @ Wd[h][t])   (fp32 path, unchanged from R2)
// ---------------------------------------------------------------------------
__global__ __launch_bounds__(256) void k_dense(
    const float* __restrict__ net, const float* __restrict__ Wd,
    float* __restrict__ tmp, int t)
{
  __shared__ __align__(16) float As[16][LDP];
  __shared__ __align__(16) float Bs[16][LDP];
  const int mt = blockIdx.x, nt = blockIdx.y, h = blockIdx.z;
  const float* A = net + (size_t)h * 1048576 + mt * 64 * 256;
  const float* Bm = Wd + (size_t)(h * TT + t) * VV * VV + nt * 64;
  float acc[4][4];
  gemm_core(A, Bm, 256, acc, As, Bs);
  const int tx = threadIdx.x & 15, ty = threadIdx.x >> 4;
#pragma unroll
  for (int i = 0; i < 4; i++) {
    int row = mt * 64 + ty * 4 + i;
    int col = nt * 64 + tx * 4;
    f4 nv = *(const f4*)&net[(size_t)h * 1048576 + row * 256 + col];
    f4 ov;
#pragma unroll
    for (int j = 0; j < 4; j++) ov[j] = nv[j] + fmaxf(acc[i][j], 0.f);
    *(f4*)&tmp[(size_t)h * 1048576 + row * 256 + col] = ov;
  }
}

// ---------------------------------------------------------------------------
// Flash attention: fp32 QK^T + softmax (numerically matches R2's passing
// kernel), split-bf16 MFMA for PV (P=Ph+Pl, V=Vh+Vl; O += PhVh+PhVl+PlVh,
// effective precision ~2^-18 -> safe under the ~1e4 error amplification).
// Block = 256 threads (16x16 for S-phase; 4 waves for MFMA). 64 q-rows/block.
// Thread rows ty*4+i coincide with MFMA C-layout rows (quad*4+r) per wave.
// grid: (16 q-tiles, 4 batch, 8 heads)
// ---------------------------------------------------------------------------
__global__ __launch_bounds__(256, 2) void k_attn(
    const float* __restrict__ qtg, const float* __restrict__ ktg,
    const short* __restrict__ vth, const short* __restrict__ vtl,
    float* __restrict__ ob)
{
  // 54,272 B total; Ks overlays the V hi/lo chunk region (time-disjoint).
  __shared__ __align__(16) char smem[54272];
  float (*Qt)[LQP]  = (float(*)[LQP])(smem);            // 17,408 B
  float (*Ks)[LQP]  = (float(*)[LQP])(smem + 17408);    // 17,408 B (overlay)
  short (*Vh)[LKP]  = (short(*)[LKP])(smem + 17408);    //  9,216 B
  short (*Vl2)[LKP] = (short(*)[LKP])(smem + 26624);    //  9,216 B
  short (*Ph)[LKP]  = (short(*)[LKP])(smem + 35840);    //  9,216 B
  short (*Pl)[LKP]  = (short(*)[LKP])(smem + 45056);    //  9,216 B

  const int qt = blockIdx.x, b = blockIdx.y, h = blockIdx.z;
  const int tid = threadIdx.x;
  const int tx = tid & 15, ty = tid >> 4;
  const int wv = tid >> 6, lane = tid & 63, ln = lane & 15, quad = lane >> 4;
  const int hb = h * 4 + b;

  const float* qg  = qtg + (size_t)hb * 65536;   // [64 feat][1024 s]
  const float* kg  = ktg + (size_t)hb * 65536;
  const short* vhg = vth + (size_t)hb * 262144;  // [256 vcol][1024 s]
  const short* vlg = vtl + (size_t)hb * 262144;

  // stage Qt[feat][row] once (coalesced f4 reads, conflict-free f4 writes)
#pragma unroll
  for (int i = 0; i < 4; i++) {
    int e = tid + i * 256;
    int f = e >> 4, c = e & 15;
    *(f4*)&Qt[f][c * 4] = *(const f4*)&qg[f * 1024 + qt * 64 + c * 4];
  }

  float m[4] = {-1e30f, -1e30f, -1e30f, -1e30f};
  float l[4] = {0.f, 0.f, 0.f, 0.f};
  f4 O[16];
#pragma unroll
  for (int nt = 0; nt < 16; nt++) O[nt] = (f4){0.f, 0.f, 0.f, 0.f};

  for (int kt = 0; kt < 16; kt++) {
    // stage Ks[feat][key]
#pragma unroll
    for (int i = 0; i < 4; i++) {
      int e = tid + i * 256;
      int f = e >> 4, c = e & 15;
      *(f4*)&Ks[f][c * 4] = *(const f4*)&kg[f * 1024 + kt * 64 + c * 4];
    }
    __syncthreads();   // B1: Ks (and Qt, first iter) visible

    // S = Q K^T (fp32, 4x4 microtile: rows ty*4+i, keys tx*4+j)
    float s[4][4];
#pragma unroll
    for (int i = 0; i < 4; i++)
#pragma unroll
      for (int j = 0; j < 4; j++) s[i][j] = 0.f;
#pragma unroll 16
    for (int kd = 0; kd < 64; kd++) {
      f4 aq = *(const f4*)&Qt[kd][ty * 4];
      f4 ak = *(const f4*)&Ks[kd][tx * 4];
#pragma unroll
      for (int i = 0; i < 4; i++)
#pragma unroll
        for (int j = 0; j < 4; j++)
          s[i][j] += aq[i] * ak[j];
    }

    // online softmax (identical numerics to R2)
    float alpha[4];
#pragma unroll
    for (int i = 0; i < 4; i++) {
#pragma unroll
      for (int j = 0; j < 4; j++) s[i][j] *= SCL;
      float mloc = fmaxf(fmaxf(s[i][0], s[i][1]), fmaxf(s[i][2], s[i][3]));
#pragma unroll
      for (int d = 1; d < 16; d <<= 1)
        mloc = fmaxf(mloc, __shfl_xor(mloc, d, 64));
      float mnew = fmaxf(m[i], mloc);
      alpha[i] = __expf(m[i] - mnew);
      float ls = 0.f;
#pragma unroll
      for (int j = 0; j < 4; j++) { s[i][j] = __expf(s[i][j] - mnew); ls += s[i][j]; }
#pragma unroll
      for (int d = 1; d < 16; d <<= 1) ls += __shfl_xor(ls, d, 64);
      l[i] = l[i] * alpha[i] + ls;
      m[i] = mnew;
    }
    // rescale O (C-layout row of reg r == ty*4+r for this lane)
#pragma unroll
    for (int nt = 0; nt < 16; nt++)
#pragma unroll
      for (int i = 0; i < 4; i++) O[nt][i] *= alpha[i];

    // P -> hi/lo bf16, write [row][key] (rows ty*4+i are wave-private)
#pragma unroll
    for (int i = 0; i < 4; i++) {
      s4v vh_, vl_;
#pragma unroll
      for (int j = 0; j < 4; j++) {
        float p = s[i][j];
        short hi = f2bf(p);
        vh_[j] = hi;
        vl_[j] = f2bf(p - bf2f(hi));
      }
      *(s4v*)&Ph[ty * 4 + i][tx * 4] = vh_;
      *(s4v*)&Pl[ty * 4 + i][tx * 4] = vl_;
    }
    __syncthreads();   // B2: all waves done reading Ks before V overlay

    // P A-fragments (wave-private rows; same-wave DS ordering)
    bf8 ph0 = *(const bf8*)&Ph[wv * 16 + ln][quad * 8];
    bf8 ph1 = *(const bf8*)&Ph[wv * 16 + ln][32 + quad * 8];
    bf8 pl0 = *(const bf8*)&Pl[wv * 16 + ln][quad * 8];
    bf8 pl1 = *(const bf8*)&Pl[wv * 16 + ln][32 + quad * 8];

    // PV: stream V in 4 chunks of 64 vcols (hi+lo planes)
    for (int c4 = 0; c4 < 4; c4++) {
#pragma unroll
      for (int i = 0; i < 2; i++) {
        int e = tid + i * 256;
        int vc = e >> 3, fc = e & 7;
        size_t gidx = (size_t)(c4 * 64 + vc) * 1024 + kt * 64 + fc * 8;
        *(bf8*)&Vh[vc][fc * 8]  = *(const bf8*)&vhg[gidx];
        *(bf8*)&Vl2[vc][fc * 8] = *(const bf8*)&vlg[gidx];
      }
      __syncthreads();  // B3: V chunk visible
#pragma unroll
      for (int n2 = 0; n2 < 4; n2++) {
        int nt = c4 * 4 + n2;
        bf8 vh0 = *(const bf8*)&Vh[n2 * 16 + ln][quad * 8];
        bf8 vh1 = *(const bf8*)&Vh[n2 * 16 + ln][32 + quad * 8];
        bf8 vl0 = *(const bf8*)&Vl2[n2 * 16 + ln][quad * 8];
        bf8 vl1 = *(const bf8*)&Vl2[n2 * 16 + ln][32 + quad * 8];
        O[nt] = __builtin_amdgcn_mfma_f32_16x16x32_bf16(ph0, vh0, O[nt], 0, 0, 0);
        O[nt] = __builtin_amdgcn_mfma_f32_16x16x32_bf16(ph1, vh1, O[nt], 0, 0, 0);
        O[nt] = __builtin_amdgcn_mfma_f32_16x16x32_bf16(ph0, vl0, O[nt], 0, 0, 0);
        O[nt] = __builtin_amdgcn_mfma_f32_16x16x32_bf16(ph1, vl1, O[nt], 0, 0, 0);
        O[nt] = __builtin_amdgcn_mfma_f32_16x16x32_bf16(pl0, vh0, O[nt], 0, 0, 0);
        O[nt] = __builtin_amdgcn_mfma_f32_16x16x32_bf16(pl1, vh1, O[nt], 0, 0, 0);
      }
      __syncthreads();  // B4: V chunk reads done before next staging
    }
  }

  // epilogue: O / l  (row = ty*4+r, col = nt*16+ln)
#pragma unroll
  for (int r = 0; r < 4; r++) {
    float linv = 1.f / l[r];
    int row = qt * 64 + ty * 4 + r;
    float* dst = ob + (size_t)h * 1048576 + (size_t)(b * 1024 + row) * 256;
#pragma unroll
    for (int nt = 0; nt < 16; nt++)
      dst[nt * 16 + ln] = O[nt][r] * linv;
  }
}

// ---------------------------------------------------------------------------
// BN stats: per (h, channel) sum and sumsq of y over 4096 rows.
// ---------------------------------------------------------------------------
__global__ __launch_bounds__(256) void k_bnstats(
    const float* __restrict__ a, const float* __restrict__ b,
    float* __restrict__ stats, int addB)
{
  const int h = blockIdx.y, r0 = blockIdx.x * 64, c = threadIdx.x;
  const float* pa = a + (size_t)h * 1048576 + r0 * 256 + c;
  float s = 0.f, s2 = 0.f;
  if (addB) {
    const float* pb = b + (size_t)h * 1048576 + r0 * 256 + c;
    for (int r = 0; r < 64; r++) {
      float y = pa[r * 256] + pb[r * 256];
      s += y; s2 += y * y;
    }
  } else {
    for (int r = 0; r < 64; r++) {
      float y = pa[r * 256];
      s += y; s2 += y * y;
    }
  }
  atomicAdd(&stats[(h * 256 + c) * 2], s);
  atomicAdd(&stats[(h * 256 + c) * 2 + 1], s2);
}

// ---------------------------------------------------------------------------
// BN apply: dst = (y - mean) * rsqrt(var+eps) * gamma + beta.
// ---------------------------------------------------------------------------
__global__ __launch_bounds__(256) void k_bnapply(
    const float* __restrict__ a, const float* __restrict__ b,
    const float* __restrict__ stats,
    const float* __restrict__ gamma, const float* __restrict__ beta,
    float* __restrict__ dst, int t, int addB, int transposed)
{
  const int h = blockIdx.y, r0 = blockIdx.x * 64, c = threadIdx.x;
  float s  = stats[(h * 256 + c) * 2];
  float s2 = stats[(h * 256 + c) * 2 + 1];
  float mean = s * (1.f / 4096.f);
  float var  = s2 * (1.f / 4096.f) - mean * mean;
  float inv  = rsqrtf(var + EPSV);
  float g  = gamma[(h * TT + t) * 256 + c] * inv;
  float bt = beta[(h * TT + t) * 256 + c];
  const float* pa = a + (size_t)h * 1048576 + r0 * 256 + c;
  const float* pb = addB ? (b + (size_t)h * 1048576 + r0 * 256 + c) : nullptr;
  for (int r = 0; r < 64; r++) {
    float y = pa[r * 256];
    if (addB) y += pb[r * 256];
    float o = (y - mean) * g + bt;
    int rg = r0 + r;
    if (transposed) dst[((size_t)rg * HH + h) * 256 + c] = o;
    else            dst[(size_t)h * 1048576 + rg * 256 + c] = o;
  }
}

// ---------------------------------------------------------------------------
extern "C" void kernel_launch(void* const* d_in, const int* in_sizes, int n_in,
                              void* d_out, int out_size, void* d_ws, size_t ws_size,
                              hipStream_t stream)
{
  const float* x   = (const float*)d_in[0];
  const float* Win = (const float*)d_in[1];
  const float* Wq  = (const float*)d_in[2];
  const float* Wk  = (const float*)d_in[3];
  const float* Wv  = (const float*)d_in[4];
  const float* Wd  = (const float*)d_in[5];
  const float* g1  = (const float*)d_in[6];
  const float* b1  = (const float*)d_in[7];
  const float* g2  = (const float*)d_in[8];
  const float* b2  = (const float*)d_in[9];
  float* out = (float*)d_out;
  float* ws  = (float*)d_ws;

  float* net   = ws;                       // H*BS*V fp32       =  8,388,608 f
  float* tmp   = net + 8388608;            // H*BS*V fp32       =  8,388,608 f
  float* stats = tmp + 8388608;            // 8 phases * H*V*2  =     32,768 f
  float* qtg   = stats + 32768;            // H*B*KD*S fp32     =  2,097,152 f
  float* ktg   = qtg + 2097152;            // H*B*KD*S fp32     =  2,097,152 f
  short* vth   = (short*)(ktg + 2097152);  // H*B*V*S bf16 hi   =  8,388,608 s
  short* vtl   = vth + 8388608;            // H*B*V*S bf16 lo   =  8,388,608 s

  hipMemsetAsync(stats, 0, 8 * HH * VV * 2 * sizeof(float), stream);

  k_in_dense<<<dim3(64, 4), 256, 0, stream>>>(x, Win, net);

  for (int t = 0; t < TT; t++) {
    k_qkv<<<dim3(64, 6, 8), 256, 0, stream>>>(net, Wq, Wk, Wv, qtg, ktg, vth, vtl, t);
    k_attn<<<dim3(16, 4, 8), 256, 0, stream>>>(qtg, ktg, vth, vtl, tmp);

    float* st1 = stats + (t * 2 + 0) * HH * VV * 2;
    k_bnstats<<<dim3(64, 8), 256, 0, stream>>>(net, tmp, st1, 1);
    k_bnapply<<<dim3(64, 8), 256, 0, stream>>>(net, tmp, st1, g1, b1, net, t, 1, 0);

    k_dense<<<dim3(64, 4, 8), 256, 0, stream>>>(net, Wd, tmp, t);

    float* st2 = stats + (t * 2 + 1) * HH * VV * 2;
    k_bnstats<<<dim3(64, 8), 256, 0, stream>>>(tmp, nullptr, st2, 0);
    if (t < TT - 1)
      k_bnapply<<<dim3(64, 8), 256, 0, stream>>>(tmp, nullptr, st2, g2, b2, net, t, 0, 0);
    else
      k_bnapply<<<dim3(64, 8), 256, 0, stream>>>(tmp, nullptr, st2, g2, b2, out, t, 0, 1);
  }
}